// Round 4
// baseline (130.380 us; speedup 1.0000x reference)
//
#include <hip/hip_runtime.h>
#include <math.h>

#define NTOK 8192
#define NEMB 8192
#define DIM  256

typedef _Float16 f16x8 __attribute__((ext_vector_type(8)));   // 4 VGPRs
typedef _Float16 f16x4 __attribute__((ext_vector_type(4)));
typedef float    f32x4 __attribute__((ext_vector_type(4)));

// ---------------------------------------------------------------------------
// Kernel A: cast X and C to fp16 (RNE); fused exact fp32 ||c||^2 and ||x||^2
// (each wave covers exactly one 256-elem row). C-branch blocks x<8 zero
// counts; X-branch blocks x<8 init keys to u64-max.
__global__ __launch_bounds__(256) void convert_kernel(
        const float* __restrict__ X, const float* __restrict__ C,
        _Float16* __restrict__ Xh, _Float16* __restrict__ Ch,
        float* __restrict__ cnorm, float* __restrict__ xnorm,
        unsigned long long* __restrict__ keys, int* __restrict__ counts) {
    const bool isC = (blockIdx.y != 0);
    if (isC && blockIdx.x < 8) {
        ((int4*)counts)[blockIdx.x * 256 + threadIdx.x] = make_int4(0, 0, 0, 0);
    }
    if (!isC && blockIdx.x < 8) {
        int4 ff = make_int4(-1, -1, -1, -1);
        ((int4*)keys)[blockIdx.x * 512 + threadIdx.x * 2]     = ff;
        ((int4*)keys)[blockIdx.x * 512 + threadIdx.x * 2 + 1] = ff;
    }
    const float* src = isC ? C : X;
    _Float16* dst = isC ? Ch : Xh;
    size_t t = (size_t)blockIdx.x * 256 + threadIdx.x;   // one float4 per thread
    float4 x = *(const float4*)&src[t * 4];
    f16x4 h;
    h[0] = (_Float16)x.x; h[1] = (_Float16)x.y;
    h[2] = (_Float16)x.z; h[3] = (_Float16)x.w;
    *(f16x4*)&dst[t * 4] = h;
    float s = x.x * x.x + x.y * x.y + x.z * x.z + x.w * x.w;
    #pragma unroll
    for (int off = 32; off >= 1; off >>= 1) s += __shfl_xor(s, off);
    if ((threadIdx.x & 63) == 0) {
        if (isC) cnorm[t >> 6] = s; else xnorm[t >> 6] = s;
    }
}

// ---------------------------------------------------------------------------
// A-only K32 staging (codes). B (tokens) no longer goes through LDS at all:
// B-frags load global->VGPR directly (L2-resident; each B row was read by
// only 2 waves, so LDS staging bought nothing and cost 1/3 of the port).
// Swizzle s(row) = (row + (row>>2)) & 3 keeps frag ds_read_b128 at 2-way.
__device__ __forceinline__ int swz(int row) { return (row + (row >> 2)) & 3; }

template<int N>
__device__ __forceinline__ void wait_vmcnt() {
    asm volatile("s_waitcnt vmcnt(%0)" :: "n"(N) : "memory");
}

// One K32 A-chunk: 1024 granules (256 rows x 4) of 16B -> 4 gload_lds/thread.
__device__ __forceinline__ void stage_a32(
        const _Float16* __restrict__ Ag, _Float16* buf, int t) {
    #pragma unroll
    for (int c = 0; c < 4; ++c) {
        int gr  = c * 256 + t;
        int row = gr >> 2;
        int kg  = (gr & 3) ^ swz(row);
        __builtin_amdgcn_global_load_lds(
            (const __attribute__((address_space(1))) void*)(Ag + (size_t)row * DIM + kg * 8),
            (__attribute__((address_space(3))) void*)(buf + (size_t)gr * 8), 16, 0, 0);
    }
}

// B-frags for K32 chunk Q: per lane 16B at token-row (wn+tn*16+lrow),
// k = Q*32 + g*8. Q*64-byte immediate folds into the load offset.
template<int Q>
__device__ __forceinline__ void load_b(
        const _Float16* const (&bbase)[4], f16x8 (&dst)[4]) {
    #pragma unroll
    for (int tn = 0; tn < 4; ++tn)
        dst[tn] = *(const f16x8*)&bbase[tn][Q * 32];
}

// 128x64 wave tile, A from LDS in two half-groups (bounds live af regs at 4),
// B from registers. 8 ds_read_b128 feed 32 MFMAs (256 B LDS-read per MFMA,
// was 384 with B in LDS).
__device__ __forceinline__ void compute_a(
        const _Float16* Abuf, const f16x8 (&bf)[4], f32x4 (&acc)[8][4],
        int wm, int lrow, int g) {
    #pragma unroll
    for (int h = 0; h < 2; ++h) {
        f16x8 af[4];
        #pragma unroll
        for (int i = 0; i < 4; ++i) {
            int row = wm + (h * 4 + i) * 16 + lrow;
            af[i] = *(const f16x8*)&Abuf[(row * 4 + (g ^ swz(row))) * 8];
        }
        __builtin_amdgcn_s_setprio(1);
        #pragma unroll
        for (int i = 0; i < 4; ++i)
            #pragma unroll
            for (int tn = 0; tn < 4; ++tn)
                acc[h * 4 + i][tn] = __builtin_amdgcn_mfma_f32_16x16x32_f16(
                    af[i], bf[tn], acc[h * 4 + i][tn], 0, 0, 0);
        __builtin_amdgcn_s_setprio(0);
    }
}

// ---------------------------------------------------------------------------
// Kernel B: fp16 distance GEMM (K=256, fp32 accum), A=codes (argmin over
// C/D rows). 256x128 block tile, 4 waves of 128x64. A: triple-buffered
// 16 KB K32 ring in LDS (counted vmcnt, single barrier per phase). B:
// double-buffered in VGPRs, loaded one phase ahead (compiler auto-wait at
// first use = vmcnt(8) -> a full phase of slack).
// Manual wait derivation (issue order per window: [wait][bar][stage A(P+2)]
// [load B(P+1)][compute P]): newer-than-A(P) = B(P-1)+A(P+1)+B(P) = 12 in
// steady state; 8 at P=0 (prologue = A0,A1,B0) and P=7.
// Epilogue: packed u64 key = bits(d+64)<<32 | code via atomicMin
// (order-isomorphic, tie -> lower code, replay-safe).
__global__ __launch_bounds__(256, 2) void mfma_argmin_kernel(
        const _Float16* __restrict__ Xh, const _Float16* __restrict__ Ch,
        const float* __restrict__ cnorm,
        unsigned long long* __restrict__ keys) {
    __shared__ __align__(16) _Float16 lds[24576];   // 48 KB: 3 x 16 KB A-ring

    const int t = threadIdx.x;
    const int wid = t >> 6, lane = t & 63;
    const int tb0 = blockIdx.x * 128;   // token block
    const int cb0 = blockIdx.y * 256;   // code block
    const int wm = (wid >> 1) * 128;    // wave's code offset (0 / 128)
    const int wn = (wid & 1) * 64;      // wave's token offset (0 / 64)
    const int lrow = lane & 15;
    const int g = lane >> 4;            // quad

    f32x4 acc[8][4];                    // [tm=codes][tn=tokens]
    #pragma unroll
    for (int a = 0; a < 8; ++a)
        #pragma unroll
        for (int b = 0; b < 4; ++b) acc[a][b] = (f32x4)0.0f;

    const _Float16* Ag = Ch + (size_t)cb0 * DIM;   // codes

    const _Float16* bbase[4];
    #pragma unroll
    for (int tn = 0; tn < 4; ++tn)
        bbase[tn] = Xh + (size_t)(tb0 + wn + tn * 16 + lrow) * DIM + g * 8;

    f16x8 bf[2][4];                     // B double-buffer (static parity idx)

    stage_a32(Ag,      lds,        t);  // A(0)
    stage_a32(Ag + 32, lds + 8192, t);  // A(1)
    load_b<0>(bbase, bf[0]);            // B(0)

#define PHASE(P, WAITN, LAST)                                                 \
    do {                                                                      \
        wait_vmcnt<WAITN>();                                                  \
        __builtin_amdgcn_s_barrier();                                         \
        __builtin_amdgcn_sched_barrier(0);                                    \
        if ((P) + 2 < 8)                                                      \
            stage_a32(Ag + ((P) + 2) * 32, lds + (((P) + 2) % 3) * 8192, t);  \
        if (!(LAST)) load_b<((P) + 1) & 7>(bbase, bf[((P) + 1) & 1]);         \
        compute_a(lds + ((P) % 3) * 8192, bf[(P) & 1], acc, wm, lrow, g);     \
        __builtin_amdgcn_sched_barrier(0);                                    \
    } while (0)

    PHASE(0,  8, false); PHASE(1, 12, false); PHASE(2, 12, false);
    PHASE(3, 12, false); PHASE(4, 12, false); PHASE(5, 12, false);
    PHASE(6, 12, false); PHASE(7,  8, true);
#undef PHASE

    // ---- epilogue: d = ||c||^2 - 2 c.x ; argmin over this block's 256 codes
    // cmb region = first 2 KB of buf0; all waves passed the phase-7 barrier
    // (after compute(6), the last buf0 reader); compute(7) reads buf1 — disjoint.
    float cn[32];
    #pragma unroll
    for (int tm = 0; tm < 8; ++tm)
        #pragma unroll
        for (int reg = 0; reg < 4; ++reg)
            cn[tm * 4 + reg] = cnorm[cb0 + wm + tm * 16 + g * 4 + reg];

    float* cmb_v = (float*)lds;                    // [128][2]
    int*   cmb_i = (int*)((float*)lds + 256);      // [128][2]

    #pragma unroll
    for (int tn = 0; tn < 4; ++tn) {
        float bv = 1e30f; int bi = 0x7fffffff;
        #pragma unroll
        for (int tm = 0; tm < 8; ++tm) {
            #pragma unroll
            for (int reg = 0; reg < 4; ++reg) {
                float d = fmaf(-2.0f, acc[tm][tn][reg], cn[tm * 4 + reg]);
                int code = cb0 + wm + tm * 16 + g * 4 + reg;  // ascending -> strict <
                if (d < bv) { bv = d; bi = code; }
            }
        }
        #pragma unroll
        for (int off = 16; off <= 32; off <<= 1) {  // reduce over the 4 quads
            float ov = __shfl_xor(bv, off);
            int   oi = __shfl_xor(bi, off);
            if (ov < bv || (ov == bv && oi < bi)) { bv = ov; bi = oi; }
        }
        if (g == 0) {
            int tl = wn + tn * 16 + lrow;           // token-local 0..127
            cmb_v[tl * 2 + (wid >> 1)] = bv;
            cmb_i[tl * 2 + (wid >> 1)] = bi;
        }
    }
    __syncthreads();
    if (t < 128) {
        float v0 = cmb_v[t * 2], v1 = cmb_v[t * 2 + 1];
        int   i0 = cmb_i[t * 2], i1 = cmb_i[t * 2 + 1];
        bool tk = (v1 < v0) || (v1 == v0 && i1 < i0);
        float bv = tk ? v1 : v0;
        int   bi = tk ? i1 : i0;
        unsigned long long key =
            ((unsigned long long)__builtin_bit_cast(unsigned, bv + 64.0f) << 32)
            | (unsigned)bi;
        atomicMin(&keys[tb0 + t], key);
    }
}

// ---------------------------------------------------------------------------
// Kernel C: unpack keys -> idx + distance, histogram via device atomics,
// gather C rows -> out, per-block loss partial (||x-c||^2 = xnorm + d) to
// psum. 256 blocks x 32 tokens.
__global__ __launch_bounds__(256) void gather_kernel(
        const float* __restrict__ C, const unsigned long long* __restrict__ keys,
        const float* __restrict__ xnorm, int* __restrict__ counts,
        float* __restrict__ out, float* __restrict__ psum) {
    __shared__ int idx_lds[32];
    const int m0 = blockIdx.x * 32;
    const int t = threadIdx.x;
    if (t < 32) {
        unsigned long long k = keys[m0 + t];
        int bi  = (int)(unsigned)k;
        float d = __builtin_bit_cast(float, (unsigned)(k >> 32)) - 64.0f;
        idx_lds[t] = bi;
        atomicAdd(&counts[bi], 1);
        float lt = d + xnorm[m0 + t];               // ||x - c||^2 for this token
        #pragma unroll
        for (int off = 1; off < 32; off <<= 1) lt += __shfl_xor(lt, off);
        if (t == 0) psum[blockIdx.x] = lt;
    }
    __syncthreads();
    const int wid = t >> 6, lane = t & 63;
    #pragma unroll
    for (int r = 0; r < 8; ++r) {
        int token = m0 + wid * 8 + r;
        int e = idx_lds[wid * 8 + r];
        float4 q = *(const float4*)&C[(size_t)e * DIM + lane * 4];
        *(float4*)&out[(size_t)token * DIM + lane * 4] = q;
    }
}

// ---------------------------------------------------------------------------
// Kernel D: entropy over the 8192-bin histogram + loss. 1024 threads x 8
// fully-unrolled loads -> 8 loads in flight/thread, 16 waves of TLP.
__global__ __launch_bounds__(1024) void finalize_kernel(
        const int* __restrict__ counts, const float* __restrict__ psum,
        float* __restrict__ out) {
    const int t = threadIdx.x;
    double local = 0.0;
    #pragma unroll
    for (int i = 0; i < 8; ++i) {
        int e = t + i * 1024;
        float p = (float)counts[e] * (1.0f / (float)NTOK);
        local += (double)(p * logf(p + 1e-10f));
    }
    float ls = (t < 256) ? psum[t] : 0.0f;   // 256 partial sums
    #pragma unroll
    for (int off = 32; off >= 1; off >>= 1) {
        local += __shfl_xor(local, off);
        ls    += __shfl_xor(ls, off);
    }
    __shared__ double she[16];
    __shared__ float  shs[16];
    int lane = t & 63, wid = t >> 6;
    if (lane == 0) { she[wid] = local; shs[wid] = ls; }
    __syncthreads();
    if (t == 0) {
        double ent = 0.0; float ssq = 0.0f;
        #pragma unroll
        for (int w = 0; w < 16; ++w) { ent += she[w]; ssq += shs[w]; }
        out[(size_t)NTOK * DIM]     = 1.25f * ssq / (float)((size_t)NTOK * DIM);
        out[(size_t)NTOK * DIM + 1] = expf((float)(-ent));
    }
}

// ---------------------------------------------------------------------------
extern "C" void kernel_launch(void* const* d_in, const int* in_sizes, int n_in,
                              void* d_out, int out_size, void* d_ws, size_t ws_size,
                              hipStream_t stream) {
    const float* X = (const float*)d_in[0];   // [32,256,256] fp32
    const float* C = (const float*)d_in[1];   // [8192,256]   fp32
    float* out = (float*)d_out;

    char* ws = (char*)d_ws;
    size_t o = 0;
    _Float16* Xh = (_Float16*)(ws + o); o += (size_t)NTOK * DIM * 2;
    _Float16* Ch = (_Float16*)(ws + o); o += (size_t)NEMB * DIM * 2;
    float* cnorm = (float*)(ws + o); o += (size_t)NEMB * 4;
    float* xnorm = (float*)(ws + o); o += (size_t)NTOK * 4;
    unsigned long long* keys = (unsigned long long*)(ws + o); o += (size_t)NTOK * 8;
    int* counts  = (int*)(ws + o);   o += (size_t)NEMB * 4;
    float* psum  = (float*)(ws + o);

    convert_kernel<<<dim3(NTOK * DIM / 4 / 256, 2), 256, 0, stream>>>(
        X, C, Xh, Ch, cnorm, xnorm, keys, counts);
    mfma_argmin_kernel<<<dim3(NTOK / 128, NEMB / 256), 256, 0, stream>>>(
        Xh, Ch, cnorm, keys);
    gather_kernel<<<256, 256, 0, stream>>>(
        C, keys, xnorm, counts, out, psum);
    finalize_kernel<<<1, 1024, 0, stream>>>(counts, psum, out);
}

// Round 5
// 117.161 us; speedup vs baseline: 1.1128x; 1.1128x over previous
//
#include <hip/hip_runtime.h>
#include <math.h>

#define NTOK 8192
#define NEMB 8192
#define DIM  256

typedef _Float16 f16x8 __attribute__((ext_vector_type(8)));   // 4 VGPRs
typedef _Float16 f16x4 __attribute__((ext_vector_type(4)));
typedef float    f32x4 __attribute__((ext_vector_type(4)));

// ---------------------------------------------------------------------------
// Kernel A: cast X and C to fp16 (RNE); fused exact fp32 ||c||^2 and ||x||^2
// (each wave covers exactly one 256-elem row). C-branch blocks x<8 zero
// counts; X-branch blocks x<8 init keys to u64-max.
__global__ __launch_bounds__(256) void convert_kernel(
        const float* __restrict__ X, const float* __restrict__ C,
        _Float16* __restrict__ Xh, _Float16* __restrict__ Ch,
        float* __restrict__ cnorm, float* __restrict__ xnorm,
        unsigned long long* __restrict__ keys, int* __restrict__ counts) {
    const bool isC = (blockIdx.y != 0);
    if (isC && blockIdx.x < 8) {
        ((int4*)counts)[blockIdx.x * 256 + threadIdx.x] = make_int4(0, 0, 0, 0);
    }
    if (!isC && blockIdx.x < 8) {
        int4 ff = make_int4(-1, -1, -1, -1);
        ((int4*)keys)[blockIdx.x * 512 + threadIdx.x * 2]     = ff;
        ((int4*)keys)[blockIdx.x * 512 + threadIdx.x * 2 + 1] = ff;
    }
    const float* src = isC ? C : X;
    _Float16* dst = isC ? Ch : Xh;
    size_t t = (size_t)blockIdx.x * 256 + threadIdx.x;   // one float4 per thread
    float4 x = *(const float4*)&src[t * 4];
    f16x4 h;
    h[0] = (_Float16)x.x; h[1] = (_Float16)x.y;
    h[2] = (_Float16)x.z; h[3] = (_Float16)x.w;
    *(f16x4*)&dst[t * 4] = h;
    float s = x.x * x.x + x.y * x.y + x.z * x.z + x.w * x.w;
    #pragma unroll
    for (int off = 32; off >= 1; off >>= 1) s += __shfl_xor(s, off);
    if ((threadIdx.x & 63) == 0) {
        if (isC) cnorm[t >> 6] = s; else xnorm[t >> 6] = s;
    }
}

// ---------------------------------------------------------------------------
// K32-chunk staging, 256x128 block tile (A=256 codes, B=128 tokens), now
// 512 threads / 8 waves of 64x64 each. B is back in LDS (the R4 B-in-reg
// experiment regressed 21%: port pressure was NOT the binding resource;
// latency at 2 waves/SIMD was). Swizzle s(row) = (row + (row>>2)) & 3 keeps
// frag ds_read_b128 at 2-way. Staging stays lane-contiguous in LDS (global
// side un-swizzled — global_load_lds needs a linear dest).
__device__ __forceinline__ int swz(int row) { return (row + (row >> 2)) & 3; }

template<int N>
__device__ __forceinline__ void wait_vmcnt() {
    asm volatile("s_waitcnt vmcnt(%0)" :: "n"(N) : "memory");
}

// One K32 chunk: A = 1024 granules (256 rows x 4), B = 512 granules
// (128 rows x 4); 16B each. With 512 threads: 2 A + 1 B = 3 gload_lds per
// thread — the vmcnt(3) in the phase loop relies on this count.
__device__ __forceinline__ void stage_k32(
        const _Float16* __restrict__ Ag, const _Float16* __restrict__ Bg,
        _Float16* bufA, _Float16* bufB, int t) {
    #pragma unroll
    for (int c = 0; c < 2; ++c) {
        int gr  = c * 512 + t;
        int row = gr >> 2;
        int kg  = (gr & 3) ^ swz(row);
        __builtin_amdgcn_global_load_lds(
            (const __attribute__((address_space(1))) void*)(Ag + (size_t)row * DIM + kg * 8),
            (__attribute__((address_space(3))) void*)(bufA + (size_t)gr * 8), 16, 0, 0);
    }
    {
        int gr  = t;
        int row = gr >> 2;
        int kg  = (gr & 3) ^ swz(row);
        __builtin_amdgcn_global_load_lds(
            (const __attribute__((address_space(1))) void*)(Bg + (size_t)row * DIM + kg * 8),
            (__attribute__((address_space(3))) void*)(bufB + (size_t)gr * 8), 16, 0, 0);
    }
}

// 64x64 wave tile: 8 ds_read_b128 feed 16 MFMAs. Smaller tile than R2's
// 128x64 — on purpose: acc drops 128->64 VGPRs so 4 waves/SIMD fit, which
// is the occupancy this latency-bound kernel is starved of.
__device__ __forceinline__ void compute_k32(
        const _Float16* Abuf, const _Float16* Bbuf, f32x4 (&acc)[4][4],
        int wm, int wn, int lrow, int g) {
    f16x8 af[4], bf_[4];
    #pragma unroll
    for (int i = 0; i < 4; ++i) {
        int row = wm + i * 16 + lrow;
        af[i] = *(const f16x8*)&Abuf[(row * 4 + (g ^ swz(row))) * 8];
    }
    #pragma unroll
    for (int j = 0; j < 4; ++j) {
        int row = wn + j * 16 + lrow;
        bf_[j] = *(const f16x8*)&Bbuf[(row * 4 + (g ^ swz(row))) * 8];
    }
    __builtin_amdgcn_s_setprio(1);
    #pragma unroll
    for (int i = 0; i < 4; ++i)
        #pragma unroll
        for (int j = 0; j < 4; ++j)
            acc[i][j] = __builtin_amdgcn_mfma_f32_16x16x32_f16(
                af[i], bf_[j], acc[i][j], 0, 0, 0);
    __builtin_amdgcn_s_setprio(0);
}

// ---------------------------------------------------------------------------
// Kernel B: fp16 distance GEMM (K=256, fp32 accum), A=codes (argmin over
// C/D rows). 256x128 block tile, 8 waves of 64x64, __launch_bounds__(512,4)
// -> <=128 VGPR/wave -> 2 blocks/CU = 16 waves/CU (was 8). Triple-buffered
// K32 ring (A 3x16KB + B 3x8KB = 72KB), single barrier + counted vmcnt(3)
// per phase (stage(P+1)'s 3 loads stay in flight across the barrier;
// stage(P+2) issued after it -> every chunk gets two phases to land).
// Epilogue: packed u64 key = bits(d+64)<<32 | code via atomicMin
// (order-isomorphic, tie -> lower code, order-independent => replay-safe).
__global__ __launch_bounds__(512, 4) void mfma_argmin_kernel(
        const _Float16* __restrict__ Xh, const _Float16* __restrict__ Ch,
        const float* __restrict__ cnorm,
        unsigned long long* __restrict__ keys) {
    __shared__ __align__(16) _Float16 lds[36864];   // 72 KB
    _Float16* const ldsB = lds + 24576;             // B ring base (48 KB in)

    const int t = threadIdx.x;                      // 0..511
    const int wid = t >> 6, lane = t & 63;
    const int tb0 = blockIdx.x * 128;   // token block
    const int cb0 = blockIdx.y * 256;   // code block
    const int wm = (wid >> 1) * 64;     // wave's code offset (0/64/128/192)
    const int wn = (wid & 1) * 64;      // wave's token offset (0/64)
    const int lrow = lane & 15;
    const int g = lane >> 4;            // quad

    f32x4 acc[4][4];                    // [tm=codes][tn=tokens] = 64 VGPRs
    #pragma unroll
    for (int a = 0; a < 4; ++a)
        #pragma unroll
        for (int b = 0; b < 4; ++b) acc[a][b] = (f32x4)0.0f;

    const _Float16* Ag = Ch + (size_t)cb0 * DIM;   // codes
    const _Float16* Bg = Xh + (size_t)tb0 * DIM;   // tokens

    stage_k32(Ag,      Bg,      lds,        ldsB,        t);  // S(0)
    stage_k32(Ag + 32, Bg + 32, lds + 8192, ldsB + 4096, t);  // S(1)

    // Phase P: vmcnt(3) -> S(P) landed (S(P+1)'s 3 in flight); barrier ->
    // all waves' S(P) visible AND all done with compute(P-1) (last reader
    // of ring slot (P+2)%3); stage S(P+2); compute(P). sched_barrier(0)
    // pins ds_reads below the barrier (rule-#18 hazard class).
#define PHASE(P, WAITN)                                                       \
    do {                                                                      \
        wait_vmcnt<WAITN>();                                                  \
        __builtin_amdgcn_s_barrier();                                         \
        __builtin_amdgcn_sched_barrier(0);                                    \
        if ((P) + 2 < 8)                                                      \
            stage_k32(Ag + ((P) + 2) * 32, Bg + ((P) + 2) * 32,               \
                      lds + (((P) + 2) % 3) * 8192,                           \
                      ldsB + (((P) + 2) % 3) * 4096, t);                      \
        compute_k32(lds + ((P) % 3) * 8192, ldsB + ((P) % 3) * 4096,          \
                    acc, wm, wn, lrow, g);                                    \
        __builtin_amdgcn_sched_barrier(0);                                    \
    } while (0)

    PHASE(0, 3); PHASE(1, 3); PHASE(2, 3); PHASE(3, 3);
    PHASE(4, 3); PHASE(5, 3); PHASE(6, 3); PHASE(7, 0);
#undef PHASE

    // ---- epilogue: d = ||c||^2 - 2 c.x ; argmin over this block's 256 codes
    // cmb = first 4 KB of A-buf0: last read by compute(6) and every wave
    // passed the phase-7 barrier after that; compute(7) reads A-buf1/B-buf1
    // (disjoint). 4 wm-groups now -> [128 tokens][4] combine slots.
    float cn[16];
    #pragma unroll
    for (int tm = 0; tm < 4; ++tm)
        #pragma unroll
        for (int reg = 0; reg < 4; ++reg)
            cn[tm * 4 + reg] = cnorm[cb0 + wm + tm * 16 + g * 4 + reg];

    float* cmb_v = (float*)lds;                    // [128][4]
    int*   cmb_i = (int*)((float*)lds + 512);      // [128][4]

    #pragma unroll
    for (int tn = 0; tn < 4; ++tn) {
        float bv = 1e30f; int bi = 0x7fffffff;
        #pragma unroll
        for (int tm = 0; tm < 4; ++tm) {
            #pragma unroll
            for (int reg = 0; reg < 4; ++reg) {
                float d = fmaf(-2.0f, acc[tm][tn][reg], cn[tm * 4 + reg]);
                int code = cb0 + wm + tm * 16 + g * 4 + reg;  // ascending -> strict <
                if (d < bv) { bv = d; bi = code; }
            }
        }
        #pragma unroll
        for (int off = 16; off <= 32; off <<= 1) {  // reduce over the 4 quads
            float ov = __shfl_xor(bv, off);
            int   oi = __shfl_xor(bi, off);
            if (ov < bv || (ov == bv && oi < bi)) { bv = ov; bi = oi; }
        }
        if (g == 0) {
            int tl = wn + tn * 16 + lrow;           // token-local 0..127
            cmb_v[tl * 4 + (wid >> 1)] = bv;
            cmb_i[tl * 4 + (wid >> 1)] = bi;
        }
    }
    __syncthreads();
    if (t < 128) {
        float bv = cmb_v[t * 4]; int bi = cmb_i[t * 4];
        #pragma unroll
        for (int w = 1; w < 4; ++w) {
            float ov = cmb_v[t * 4 + w];
            int   oi = cmb_i[t * 4 + w];
            if (ov < bv || (ov == bv && oi < bi)) { bv = ov; bi = oi; }
        }
        unsigned long long key =
            ((unsigned long long)__builtin_bit_cast(unsigned, bv + 64.0f) << 32)
            | (unsigned)bi;
        atomicMin(&keys[tb0 + t], key);
    }
}

// ---------------------------------------------------------------------------
// Kernel C: unpack keys -> idx + distance, histogram via device atomics,
// gather C rows -> out, per-block loss partial (||x-c||^2 = xnorm + d) to
// psum. 256 blocks x 32 tokens.
__global__ __launch_bounds__(256) void gather_kernel(
        const float* __restrict__ C, const unsigned long long* __restrict__ keys,
        const float* __restrict__ xnorm, int* __restrict__ counts,
        float* __restrict__ out, float* __restrict__ psum) {
    __shared__ int idx_lds[32];
    const int m0 = blockIdx.x * 32;
    const int t = threadIdx.x;
    if (t < 32) {
        unsigned long long k = keys[m0 + t];
        int bi  = (int)(unsigned)k;
        float d = __builtin_bit_cast(float, (unsigned)(k >> 32)) - 64.0f;
        idx_lds[t] = bi;
        atomicAdd(&counts[bi], 1);
        float lt = d + xnorm[m0 + t];               // ||x - c||^2 for this token
        #pragma unroll
        for (int off = 1; off < 32; off <<= 1) lt += __shfl_xor(lt, off);
        if (t == 0) psum[blockIdx.x] = lt;
    }
    __syncthreads();
    const int wid = t >> 6, lane = t & 63;
    #pragma unroll
    for (int r = 0; r < 8; ++r) {
        int token = m0 + wid * 8 + r;
        int e = idx_lds[wid * 8 + r];
        float4 q = *(const float4*)&C[(size_t)e * DIM + lane * 4];
        *(float4*)&out[(size_t)token * DIM + lane * 4] = q;
    }
}

// ---------------------------------------------------------------------------
// Kernel D: entropy over the 8192-bin histogram + loss. 1024 threads x 8
// fully-unrolled loads -> 8 loads in flight/thread, 16 waves of TLP.
__global__ __launch_bounds__(1024) void finalize_kernel(
        const int* __restrict__ counts, const float* __restrict__ psum,
        float* __restrict__ out) {
    const int t = threadIdx.x;
    double local = 0.0;
    #pragma unroll
    for (int i = 0; i < 8; ++i) {
        int e = t + i * 1024;
        float p = (float)counts[e] * (1.0f / (float)NTOK);
        local += (double)(p * logf(p + 1e-10f));
    }
    float ls = (t < 256) ? psum[t] : 0.0f;   // 256 partial sums
    #pragma unroll
    for (int off = 32; off >= 1; off >>= 1) {
        local += __shfl_xor(local, off);
        ls    += __shfl_xor(ls, off);
    }
    __shared__ double she[16];
    __shared__ float  shs[16];
    int lane = t & 63, wid = t >> 6;
    if (lane == 0) { she[wid] = local; shs[wid] = ls; }
    __syncthreads();
    if (t == 0) {
        double ent = 0.0; float ssq = 0.0f;
        #pragma unroll
        for (int w = 0; w < 16; ++w) { ent += she[w]; ssq += shs[w]; }
        out[(size_t)NTOK * DIM]     = 1.25f * ssq / (float)((size_t)NTOK * DIM);
        out[(size_t)NTOK * DIM + 1] = expf((float)(-ent));
    }
}

// ---------------------------------------------------------------------------
extern "C" void kernel_launch(void* const* d_in, const int* in_sizes, int n_in,
                              void* d_out, int out_size, void* d_ws, size_t ws_size,
                              hipStream_t stream) {
    const float* X = (const float*)d_in[0];   // [32,256,256] fp32
    const float* C = (const float*)d_in[1];   // [8192,256]   fp32
    float* out = (float*)d_out;

    char* ws = (char*)d_ws;
    size_t o = 0;
    _Float16* Xh = (_Float16*)(ws + o); o += (size_t)NTOK * DIM * 2;
    _Float16* Ch = (_Float16*)(ws + o); o += (size_t)NEMB * DIM * 2;
    float* cnorm = (float*)(ws + o); o += (size_t)NEMB * 4;
    float* xnorm = (float*)(ws + o); o += (size_t)NTOK * 4;
    unsigned long long* keys = (unsigned long long*)(ws + o); o += (size_t)NTOK * 8;
    int* counts  = (int*)(ws + o);   o += (size_t)NEMB * 4;
    float* psum  = (float*)(ws + o);

    convert_kernel<<<dim3(NTOK * DIM / 4 / 256, 2), 256, 0, stream>>>(
        X, C, Xh, Ch, cnorm, xnorm, keys, counts);
    mfma_argmin_kernel<<<dim3(NTOK / 128, NEMB / 256), 512, 0, stream>>>(
        Xh, Ch, cnorm, keys);
    gather_kernel<<<256, 256, 0, stream>>>(
        C, keys, xnorm, counts, out, psum);
    finalize_kernel<<<1, 1024, 0, stream>>>(counts, psum, out);
}